// Round 1
// baseline (78.943 us; speedup 1.0000x reference)
//
#include <hip/hip_runtime.h>

#define NPART 4096
#define DIM 32
#define TJ 64

// ---------------------------------------------------------------------------
// norms[r] = ||x_r||^2
__global__ __launch_bounds__(256) void svgd_norms_kernel(const float* __restrict__ X,
                                                         float* __restrict__ norms) {
  int row = blockIdx.x * 256 + threadIdx.x;
  const float4* xr = reinterpret_cast<const float4*>(X + (size_t)row * DIM);
  float d0 = 0.f, d1 = 0.f, d2 = 0.f, d3 = 0.f;
#pragma unroll
  for (int q = 0; q < 8; ++q) {
    float4 a = xr[q];
    d0 = fmaf(a.x, a.x, d0);
    d1 = fmaf(a.y, a.y, d1);
    d2 = fmaf(a.z, a.z, d2);
    d3 = fmaf(a.w, a.w, d3);
  }
  norms[row] = (d0 + d1) + (d2 + d3);
}

// ---------------------------------------------------------------------------
// Each thread owns one row i. Block handles a chunk of j of length jchunk
// (blockIdx.y selects the chunk). Partial T (sum k*x_j) and S (sum k) written
// to workspace.
__global__ __launch_bounds__(256, 4) void svgd_main_kernel(
    const float* __restrict__ X, const float* __restrict__ ls,
    const float* __restrict__ norms, float* __restrict__ pT,
    float* __restrict__ pS, int jchunk) {
  __shared__ float4 sX[TJ * 8];  // TJ rows of 32 floats
  __shared__ float sN[TJ];

  const int tid = threadIdx.x;
  const int row = blockIdx.x * 256 + tid;

  const float lsv = ls[0];
  const float inv2 = 0.5f / (lsv * lsv);

  float4 xi[8];
  const float4* xr = reinterpret_cast<const float4*>(X + (size_t)row * DIM);
#pragma unroll
  for (int q = 0; q < 8; ++q) xi[q] = xr[q];
  const float ni = norms[row];

  float4 acc[8];
#pragma unroll
  for (int q = 0; q < 8; ++q) acc[q] = make_float4(0.f, 0.f, 0.f, 0.f);
  float S = 0.f;

  const int j0 = blockIdx.y * jchunk;
  for (int jb = 0; jb < jchunk; jb += TJ) {
    __syncthreads();
    const float4* src = reinterpret_cast<const float4*>(X + (size_t)(j0 + jb) * DIM);
    for (int t = tid; t < TJ * 8; t += 256) sX[t] = src[t];
    if (tid < TJ) sN[tid] = norms[j0 + jb + tid];
    __syncthreads();

#pragma unroll 2
    for (int t = 0; t < TJ; ++t) {
      const float4* xj = &sX[t * 8];
      float4 v[8];
#pragma unroll
      for (int q = 0; q < 8; ++q) v[q] = xj[q];  // wave-uniform LDS broadcast
      float d0 = 0.f, d1 = 0.f, d2 = 0.f, d3 = 0.f;
#pragma unroll
      for (int q = 0; q < 8; ++q) {
        d0 = fmaf(xi[q].x, v[q].x, d0);
        d1 = fmaf(xi[q].y, v[q].y, d1);
        d2 = fmaf(xi[q].z, v[q].z, d2);
        d3 = fmaf(xi[q].w, v[q].w, d3);
      }
      float dot = (d0 + d1) + (d2 + d3);
      float argv = (2.f * dot - ni - sN[t]) * inv2;  // = -||xi-xj||^2/(2 l^2)
      float k = __expf(argv);
      S += k;
#pragma unroll
      for (int q = 0; q < 8; ++q) {
        acc[q].x = fmaf(k, v[q].x, acc[q].x);
        acc[q].y = fmaf(k, v[q].y, acc[q].y);
        acc[q].z = fmaf(k, v[q].z, acc[q].z);
        acc[q].w = fmaf(k, v[q].w, acc[q].w);
      }
    }
  }

  float4* outT = reinterpret_cast<float4*>(pT + ((size_t)blockIdx.y * NPART + row) * DIM);
#pragma unroll
  for (int q = 0; q < 8; ++q) outT[q] = acc[q];
  pS[(size_t)blockIdx.y * NPART + row] = S;
}

// ---------------------------------------------------------------------------
// out[i,d] = (inv*S_i*x[i,d] - (1+inv)*T_i[d]) / N
__global__ __launch_bounds__(256) void svgd_reduce_kernel(
    const float* __restrict__ X, const float* __restrict__ ls,
    const float* __restrict__ pT, const float* __restrict__ pS, int nsplit,
    float* __restrict__ out) {
  int idx = blockIdx.x * 256 + threadIdx.x;  // over N*DIM
  int row = idx >> 5;
  float T = 0.f, S = 0.f;
  for (int s = 0; s < nsplit; ++s) {
    T += pT[(size_t)s * NPART * DIM + idx];
    S += pS[(size_t)s * NPART + row];
  }
  const float lsv = ls[0];
  const float inv = 1.f / (lsv * lsv);
  out[idx] = (inv * S * X[idx] - (1.f + inv) * T) * (1.f / NPART);
}

// ---------------------------------------------------------------------------
// Fallback if workspace is too small: single pass, direct diff, writes out.
__global__ __launch_bounds__(256) void svgd_direct_kernel(const float* __restrict__ X,
                                                          const float* __restrict__ ls,
                                                          float* __restrict__ out) {
  __shared__ float4 sX[TJ * 8];
  const int tid = threadIdx.x;
  const int row = blockIdx.x * 256 + tid;
  const float lsv = ls[0];
  const float ls2 = lsv * lsv;
  const float inv2 = 0.5f / ls2;
  float4 xi[8];
  const float4* xr = reinterpret_cast<const float4*>(X + (size_t)row * DIM);
#pragma unroll
  for (int q = 0; q < 8; ++q) xi[q] = xr[q];
  float4 acc[8];
#pragma unroll
  for (int q = 0; q < 8; ++q) acc[q] = make_float4(0.f, 0.f, 0.f, 0.f);
  float S = 0.f;
  for (int jb = 0; jb < NPART; jb += TJ) {
    __syncthreads();
    const float4* src = reinterpret_cast<const float4*>(X + (size_t)jb * DIM);
    for (int t = tid; t < TJ * 8; t += 256) sX[t] = src[t];
    __syncthreads();
    for (int t = 0; t < TJ; ++t) {
      const float4* xj = &sX[t * 8];
      float4 v[8];
      float d0 = 0.f, d1 = 0.f, d2 = 0.f, d3 = 0.f;
#pragma unroll
      for (int q = 0; q < 8; ++q) {
        v[q] = xj[q];
        float ax = xi[q].x - v[q].x; d0 = fmaf(ax, ax, d0);
        float ay = xi[q].y - v[q].y; d1 = fmaf(ay, ay, d1);
        float az = xi[q].z - v[q].z; d2 = fmaf(az, az, d2);
        float aw = xi[q].w - v[q].w; d3 = fmaf(aw, aw, d3);
      }
      float k = __expf(-((d0 + d1) + (d2 + d3)) * inv2);
      S += k;
#pragma unroll
      for (int q = 0; q < 8; ++q) {
        acc[q].x = fmaf(k, v[q].x, acc[q].x);
        acc[q].y = fmaf(k, v[q].y, acc[q].y);
        acc[q].z = fmaf(k, v[q].z, acc[q].z);
        acc[q].w = fmaf(k, v[q].w, acc[q].w);
      }
    }
  }
  const float inv = 1.f / ls2;
  const float c1 = inv * S;
  const float c2 = 1.f + inv;
  float4* o = reinterpret_cast<float4*>(out + (size_t)row * DIM);
#pragma unroll
  for (int q = 0; q < 8; ++q) {
    float4 r;
    r.x = (c1 * xi[q].x - c2 * acc[q].x) * (1.f / NPART);
    r.y = (c1 * xi[q].y - c2 * acc[q].y) * (1.f / NPART);
    r.z = (c1 * xi[q].z - c2 * acc[q].z) * (1.f / NPART);
    r.w = (c1 * xi[q].w - c2 * acc[q].w) * (1.f / NPART);
    o[q] = r;
  }
}

// ---------------------------------------------------------------------------
extern "C" void kernel_launch(void* const* d_in, const int* in_sizes, int n_in,
                              void* d_out, int out_size, void* d_ws, size_t ws_size,
                              hipStream_t stream) {
  const float* X = (const float*)d_in[0];
  const float* ls = (const float*)d_in[1];
  float* out = (float*)d_out;
  float* ws = (float*)d_ws;

  // ws bytes needed for nsplit n: 4*(4096 + n*4096*32 + n*4096) = 16384*(1+33n)
  int nsplit = 64;
  while (nsplit > 1 && (size_t)16384 * (size_t)(1 + 33 * nsplit) > ws_size) nsplit >>= 1;

  if ((size_t)16384 * 34 > ws_size) {
    // Not even nsplit=1 fits: slow but correct single-pass path, no ws.
    svgd_direct_kernel<<<NPART / 256, 256, 0, stream>>>(X, ls, out);
    return;
  }

  float* norms = ws;
  float* pT = ws + NPART;
  float* pS = pT + (size_t)nsplit * NPART * DIM;

  svgd_norms_kernel<<<NPART / 256, 256, 0, stream>>>(X, norms);
  dim3 grid(NPART / 256, nsplit);
  svgd_main_kernel<<<grid, 256, 0, stream>>>(X, ls, norms, pT, pS, NPART / nsplit);
  svgd_reduce_kernel<<<(NPART * DIM) / 256, 256, 0, stream>>>(X, ls, pT, pS, nsplit, out);
}